// Round 1
// baseline (224.608 us; speedup 1.0000x reference)
//
#include <hip/hip_runtime.h>

#define ALPHA 0.1f
#define NUM_CLASSES 10

// ---------------------------------------------------------------------------
// Workspace layout (floats/uints):
//   ct[64*256]   : centers transposed, ct[j*256 + k] = centers[k*64 + j]
//   c2[256]      : ||c_k||^2
//   loss_acc[1]  : float loss accumulator
//   counts[100]  : uint counts[cluster<10][label]
// ---------------------------------------------------------------------------

__global__ __launch_bounds__(256) void prep_kernel(
    const float* __restrict__ centers,
    float* __restrict__ ct,
    float* __restrict__ c2,
    float* __restrict__ loss_acc,
    unsigned int* __restrict__ counts)
{
    const int k = threadIdx.x;  // 0..255, one center per thread
    const float4* crow = (const float4*)(centers + k * 64);
    float s = 0.f;
#pragma unroll
    for (int j4 = 0; j4 < 16; ++j4) {
        float4 v = crow[j4];
        int j = j4 * 4;
        ct[(j + 0) * 256 + k] = v.x;
        ct[(j + 1) * 256 + k] = v.y;
        ct[(j + 2) * 256 + k] = v.z;
        ct[(j + 3) * 256 + k] = v.w;
        s += v.x * v.x + v.y * v.y + v.z * v.z + v.w * v.w;
    }
    c2[k] = s;
    if (k < NUM_CLASSES * NUM_CLASSES) counts[k] = 0u;
    if (k == 0) loss_acc[0] = 0.f;
}

// ---------------------------------------------------------------------------
// Main kernel: block = 64 points x 256 centers. 4 waves/block.
// lane  = point (64 points per block)
// wave  = 64-center chunk; center values are wave-uniform -> s_load (SMEM),
//         keeping the VALU pipe as the only hot pipe.
// ---------------------------------------------------------------------------

__global__ __launch_bounds__(256) void dist_kernel(
    const float* __restrict__ x,
    const int*   __restrict__ y,
    const float* __restrict__ ct,
    const float* __restrict__ c2,
    float* __restrict__ loss_acc,
    unsigned int* __restrict__ counts,
    int N)
{
    const int wave = __builtin_amdgcn_readfirstlane(threadIdx.x >> 6);
    const int lane = threadIdx.x & 63;
    const int m = blockIdx.x * 64 + lane;   // point index (N % 64 == 0)
    const int kbase = wave * 64;            // this wave's center chunk

    const float* __restrict__ xrow = x + (size_t)m * 64;

    float acc[64];
#pragma unroll
    for (int k = 0; k < 64; ++k) acc[k] = 0.f;
    float x2 = 0.f;

    for (int j4 = 0; j4 < 16; ++j4) {
        float4 xv = ((const float4*)xrow)[j4];
        x2 += xv.x * xv.x + xv.y * xv.y + xv.z * xv.z + xv.w * xv.w;
        const float* __restrict__ cr0 = ct + (j4 * 4 + 0) * 256 + kbase;
        const float* __restrict__ cr1 = ct + (j4 * 4 + 1) * 256 + kbase;
        const float* __restrict__ cr2 = ct + (j4 * 4 + 2) * 256 + kbase;
        const float* __restrict__ cr3 = ct + (j4 * 4 + 3) * 256 + kbase;
#pragma unroll
        for (int k = 0; k < 64; ++k) acc[k] = fmaf(xv.x, cr0[k], acc[k]);
#pragma unroll
        for (int k = 0; k < 64; ++k) acc[k] = fmaf(xv.y, cr1[k], acc[k]);
#pragma unroll
        for (int k = 0; k < 64; ++k) acc[k] = fmaf(xv.z, cr2[k], acc[k]);
#pragma unroll
        for (int k = 0; k < 64; ++k) acc[k] = fmaf(xv.w, cr3[k], acc[k]);
    }

    // Epilogue: per-lane over this wave's 64 centers.
    float swe = 0.f, swd = 0.f;
    float dmin = 3.4e38f;
    int kmin = 0;
#pragma unroll
    for (int k = 0; k < 64; ++k) {
        float d = x2 + c2[kbase + k] - 2.f * acc[k];
        d = fmaxf(d, 0.f);
        if (d < dmin) { dmin = d; kmin = k; }   // strict < : first-min in k order
        // (1+d)^(-alpha) = exp2(-alpha * log2(1+d))
        float w = exp2f(-ALPHA * __log2f(1.f + d));
        swe += w;
        swd += w * d;
    }

    // Cross-wave combine (4 waves cover 256 centers of the same 64 points).
    __shared__ float s_swe[4][64];
    __shared__ float s_swd[4][64];
    __shared__ float s_dmin[4][64];
    __shared__ int   s_kmin[4][64];
    s_swe[wave][lane] = swe;
    s_swd[wave][lane] = swd;
    s_dmin[wave][lane] = dmin;
    s_kmin[wave][lane] = kbase + kmin;
    __syncthreads();

    if (wave == 0) {
        float SWE = s_swe[0][lane];
        float SWD = s_swd[0][lane];
        float best = s_dmin[0][lane];
        int bk = s_kmin[0][lane];
#pragma unroll
        for (int w = 1; w < 4; ++w) {
            SWE += s_swe[w][lane];
            SWD += s_swd[w][lane];
            float dv = s_dmin[w][lane];
            int kv = s_kmin[w][lane];
            if (dv < best) { best = dv; bk = kv; }  // strict < keeps lowest wave on ties
        }
        float loss_n = SWD / SWE;

        if (bk < NUM_CLASSES) {
            int label = y[m];
            atomicAdd(&counts[bk * NUM_CLASSES + label], 1u);
        }

        // Reduce loss across the 64 lanes (one point each) -> one atomic/block.
#pragma unroll
        for (int off = 32; off > 0; off >>= 1)
            loss_n += __shfl_down(loss_n, off, 64);
        if (lane == 0) atomicAdd(loss_acc, loss_n);
    }
}

// ---------------------------------------------------------------------------
// Finalize: greedy cluster->label assignment, exactly mirroring the reference.
// ---------------------------------------------------------------------------

__global__ void finalize_kernel(
    const float* __restrict__ loss_acc,
    const unsigned int* __restrict__ counts,
    float* __restrict__ out,
    int N)
{
    if (threadIdx.x == 0 && blockIdx.x == 0) {
        float c[NUM_CLASSES][NUM_CLASSES];
        for (int i = 0; i < NUM_CLASSES; ++i)
            for (int j = 0; j < NUM_CLASSES; ++j)
                c[i][j] = (float)counts[i * NUM_CLASSES + j];

        bool used[NUM_CLASSES];
        for (int i = 0; i < NUM_CLASSES; ++i) used[i] = false;

        float correct = 0.f;
        for (int i = 0; i < NUM_CLASSES; ++i) {
            float rowsum = 0.f;
            for (int j = 0; j < NUM_CLASSES; ++j) rowsum += c[i][j];
            bool has_points = rowsum > 0.f;

            // first-index argmax of the raw row
            int label = 0;
            float mx = c[i][0];
            for (int j = 1; j < NUM_CLASSES; ++j)
                if (c[i][j] > mx) { mx = c[i][j]; label = j; }

            if (used[label]) {
                // first-index argmax of the used-masked row
                float mm = used[0] ? 0.f : c[i][0];
                int l2 = 0;
                for (int j = 1; j < NUM_CLASSES; ++j) {
                    float v = used[j] ? 0.f : c[i][j];
                    if (v > mm) { mm = v; l2 = j; }
                }
                label = l2;
            }

            if (has_points) {
                correct += c[i][label];
                used[label] = true;
            }
        }
        out[0] = loss_acc[0];
        out[1] = correct / (float)N;
    }
}

// ---------------------------------------------------------------------------

extern "C" void kernel_launch(void* const* d_in, const int* in_sizes, int n_in,
                              void* d_out, int out_size, void* d_ws, size_t ws_size,
                              hipStream_t stream)
{
    const float* x       = (const float*)d_in[0];
    const int*   y       = (const int*)d_in[1];
    const float* centers = (const float*)d_in[2];
    float* out = (float*)d_out;

    const int N = in_sizes[0] / 64;  // D = 64

    float* ct = (float*)d_ws;                         // 64*256 floats
    float* c2 = ct + 64 * 256;                        // 256 floats
    float* loss_acc = c2 + 256;                       // 1 float
    unsigned int* counts = (unsigned int*)(loss_acc + 1);  // 100 uints

    prep_kernel<<<1, 256, 0, stream>>>(centers, ct, c2, loss_acc, counts);
    dist_kernel<<<N / 64, 256, 0, stream>>>(x, y, ct, c2, loss_acc, counts, N);
    finalize_kernel<<<1, 64, 0, stream>>>(loss_acc, counts, out, N);
}